// Round 1
// baseline (184.625 us; speedup 1.0000x reference)
//
#include <hip/hip_runtime.h>
#include <hip/hip_bf16.h>

// Gather: out[row, :] = features[rules[row], :], C = 64 floats (256 B/row).
// 16 threads per row, each moving one float4 (16 B). Block = 256 threads
// = 16 rows; wave64 covers 4 rows -> 1 KiB per coalesced store instruction.

#define C_FLOAT4 16   // 64 floats = 16 float4
#define ROWS_PER_BLOCK 16

__global__ __launch_bounds__(256) void BLOutputLayer_gather_kernel(
    const float4* __restrict__ features,  // [N_ACTIVE, 16] as float4
    const int* __restrict__ rules,        // [N_ROWS]
    float4* __restrict__ out,             // [N_ROWS, 16] as float4
    int n_rows) {
    const int tid  = threadIdx.x;
    const int lane = tid & (C_FLOAT4 - 1);          // which float4 within row
    const int row  = blockIdx.x * ROWS_PER_BLOCK + (tid >> 4);
    if (row >= n_rows) return;

    const int src = rules[row];                      // broadcast within 16-thread group (L1 serves)
    out[(size_t)row * C_FLOAT4 + lane] = features[(size_t)src * C_FLOAT4 + lane];
}

extern "C" void kernel_launch(void* const* d_in, const int* in_sizes, int n_in,
                              void* d_out, int out_size, void* d_ws, size_t ws_size,
                              hipStream_t stream) {
    const float4* features = (const float4*)d_in[0];
    const int*    rules    = (const int*)d_in[1];
    float4*       out      = (float4*)d_out;

    const int n_rows = in_sizes[1];                 // 524288
    const int grid   = (n_rows + ROWS_PER_BLOCK - 1) / ROWS_PER_BLOCK;

    BLOutputLayer_gather_kernel<<<grid, 256, 0, stream>>>(features, rules, out, n_rows);
}

// Round 2
// 182.663 us; speedup vs baseline: 1.0107x; 1.0107x over previous
//
#include <hip/hip_runtime.h>
#include <hip/hip_bf16.h>

// Gather: out[row, :] = features[rules[row], :], C = 64 floats (256 B/row).
//
// R2 structure: 256 rows per block. Stage rules in LDS (one coalesced pass),
// then each thread owns lane = tid&15 (one float4 within a row) and 16 rows
// strided by 16. All 16 feature loads are issued back-to-back (independent,
// 16 outstanding vmem ops per thread) before the stores, giving the MLP the
// round-1 one-shot kernel lacked. Stores stay fully coalesced: per store
// instruction a wave writes 4 consecutive rows = 1 KiB contiguous.
// Non-temporal stores keep the streamed 134 MB output from evicting the
// 51 MB features table out of L2.

typedef float f4 __attribute__((ext_vector_type(4)));

#define BLOCK 256
#define ROWS_PER_BLOCK 256
#define C_F4 16            // 64 floats = 16 float4
#define ROWS_PER_THREAD 16 // ROWS_PER_BLOCK / (BLOCK / C_F4)

__global__ __launch_bounds__(BLOCK) void BLOutputLayer_gather_kernel(
    const f4* __restrict__ features,   // [N_ACTIVE, 16] as float4
    const int* __restrict__ rules,     // [N_ROWS]
    f4* __restrict__ out,              // [N_ROWS, 16] as float4
    int n_rows) {
    __shared__ int lds_rules[ROWS_PER_BLOCK];

    const int t    = threadIdx.x;
    const int base = blockIdx.x * ROWS_PER_BLOCK;

    // Stage this block's rule indices (coalesced, one dword/thread).
    {
        const int r = base + t;
        lds_rules[t] = (r < n_rows) ? rules[r] : 0;
    }
    __syncthreads();

    const int lane = t & (C_F4 - 1);   // float4 index within a row
    const int g    = t >> 4;           // row-group 0..15

    if (base + ROWS_PER_BLOCK <= n_rows) {
        int src[ROWS_PER_THREAD];
#pragma unroll
        for (int j = 0; j < ROWS_PER_THREAD; ++j)
            src[j] = lds_rules[g + C_F4 * j];       // broadcast within 16-thread group

        f4 v[ROWS_PER_THREAD];
#pragma unroll
        for (int j = 0; j < ROWS_PER_THREAD; ++j)   // 16 independent loads in flight
            v[j] = features[(size_t)src[j] * C_F4 + lane];

#pragma unroll
        for (int j = 0; j < ROWS_PER_THREAD; ++j) {
            const int row = base + g + C_F4 * j;
            __builtin_nontemporal_store(v[j], &out[(size_t)row * C_F4 + lane]);
        }
    } else {
        // Tail tile (unused at N_ROWS = 2048*256, kept for safety).
        for (int j = 0; j < ROWS_PER_THREAD; ++j) {
            const int row = base + g + C_F4 * j;
            if (row < n_rows) {
                const int s = lds_rules[g + C_F4 * j];
                out[(size_t)row * C_F4 + lane] = features[(size_t)s * C_F4 + lane];
            }
        }
    }
}

extern "C" void kernel_launch(void* const* d_in, const int* in_sizes, int n_in,
                              void* d_out, int out_size, void* d_ws, size_t ws_size,
                              hipStream_t stream) {
    const f4*  features = (const f4*)d_in[0];
    const int* rules    = (const int*)d_in[1];
    f4*        out      = (f4*)d_out;

    const int n_rows = in_sizes[1];                          // 524288
    const int grid   = (n_rows + ROWS_PER_BLOCK - 1) / ROWS_PER_BLOCK;  // 2048

    BLOutputLayer_gather_kernel<<<grid, BLOCK, 0, stream>>>(features, rules, out, n_rows);
}